// Round 2
// baseline (98.553 us; speedup 1.0000x reference)
//
#include <hip/hip_runtime.h>
#include <hip/hip_bf16.h>

// SwitchLinear: out[b,o] = sum_i x[b,i]*W[o,i,c_b] + bias[o,c_b]
// dtypes per reference: x,W,bias,out = fp32; idx = int32. B=8192 I=O=256 C=32.
#define NB 8192
#define NI 256
#define NO 256
#define NC 32

typedef __attribute__((ext_vector_type(8))) short short8;   // 8 x bf16
typedef __attribute__((ext_vector_type(4))) float floatx4;  // MFMA acc

// ---- workspace layout (bytes) ----
// [0, 128)        : uint counts[NC]
// [4K, 4K+512K)   : ushort lists[NC][NB]
// [1M, 1M+4M)     : ushort xb[NB][NI]        (bf16 bits)
// [5M, 5M+4M)     : ushort wT[NC][NO][NI]    (bf16 bits)
#define WS_COUNTS_OFF 0
#define WS_LISTS_OFF  (4u << 10)
#define WS_XB_OFF     (1u << 20)
#define WS_WT_OFF     (5u << 20)

static __device__ __forceinline__ unsigned short f2bf(float f) {
    __hip_bfloat16 h = __float2bfloat16(f);   // RNE
    return *(unsigned short*)&h;
}

__global__ void k_bucket(const int* __restrict__ idx,
                         unsigned int* __restrict__ counts,
                         unsigned short* __restrict__ lists) {
    int b = blockIdx.x * 256 + threadIdx.x;
    int c = idx[b] & (NC - 1);
    unsigned int slot = atomicAdd(&counts[c], 1u);
    lists[c * NB + slot] = (unsigned short)b;
}

// xb = bf16(x), 8 elements/thread
__global__ void k_convert_x(const float* __restrict__ x,
                            unsigned short* __restrict__ xb) {
    size_t t = (size_t)blockIdx.x * 256 + threadIdx.x;   // 0..262143
    const float4* src = (const float4*)(x + t * 8);
    float4 a = src[0], b = src[1];
    unsigned short r[8];
    r[0] = f2bf(a.x); r[1] = f2bf(a.y); r[2] = f2bf(a.z); r[3] = f2bf(a.w);
    r[4] = f2bf(b.x); r[5] = f2bf(b.y); r[6] = f2bf(b.z); r[7] = f2bf(b.w);
    *(uint4*)(xb + t * 8) = *(uint4*)r;
}

// wT[c][o][i] = bf16(W[o][i][c]); W fp32 [NO][NI][NC], C contiguous.
__global__ void k_transpose(const float* __restrict__ w,
                            unsigned short* __restrict__ wT) {
    int g = blockIdx.x * 256 + threadIdx.x;   // g = o*NI + i, 0..65535
    const float4* src = (const float4*)(w + (size_t)g * NC);
    unsigned short vals[NC];
#pragma unroll
    for (int s = 0; s < 8; ++s) {
        float4 v = src[s];
        vals[s * 4 + 0] = f2bf(v.x);
        vals[s * 4 + 1] = f2bf(v.y);
        vals[s * 4 + 2] = f2bf(v.z);
        vals[s * 4 + 3] = f2bf(v.w);
    }
#pragma unroll
    for (int c = 0; c < NC; ++c) {
        // fixed c: 64 consecutive g per wave -> 128 B contiguous store
        wT[(size_t)c * (NO * NI) + g] = vals[c];
    }
}

// Grouped GEMM: grid (c, o-tile, m-tile), block = 256 = 4 waves.
// Tile M=64 (gathered samples), N=64 outputs, K streamed 2 x 128 (bf16 LDS).
// LDS rows padded to 136 bf16 (272 B, 16B-aligned; 68 dw == 4 mod 32 -> 2-way free).
__launch_bounds__(256)
__global__ void k_gemm(const unsigned short* __restrict__ xb,
                       const unsigned short* __restrict__ wT,
                       const float* __restrict__ bias,
                       const unsigned int* __restrict__ counts,
                       const unsigned short* __restrict__ lists,
                       float* __restrict__ out) {
    const int c  = blockIdx.x;
    const int o0 = blockIdx.y * 64;
    const int cnt = (int)counts[c];
    const int m0 = blockIdx.z * 64;
    if (m0 >= cnt) return;   // uniform dead-tile exit

    __shared__ unsigned short As[64][136];
    __shared__ unsigned short Bs[64][136];
    __shared__ int blist[64];

    const int tid = threadIdx.x;
    if (tid < 64) {
        int mr = m0 + tid;
        blist[tid] = (int)lists[c * NB + (mr < cnt ? mr : m0)];
    }
    __syncthreads();

    const int wv   = tid >> 6;
    const int lane = tid & 63;
    const int lrc  = lane & 15;        // A row m / B,D col n
    const int koff = (lane >> 4) * 8;  // k offset within 32-chunk

    floatx4 acc[4];
#pragma unroll
    for (int ms = 0; ms < 4; ++ms) acc[ms] = (floatx4){0.f, 0.f, 0.f, 0.f};

    const unsigned short* wTc = wT + ((size_t)c * NO + o0) * NI;

#pragma unroll
    for (int kt = 0; kt < 2; ++kt) {
        const int kb = kt * 128;
#pragma unroll
        for (int s = 0; s < 4; ++s) {
            int lin = tid + s * 256;   // 0..1023: 64 rows x 8 segs of 16B
            int row = lin >> 4;
            int c8  = (lin & 15) * 8;
            *(uint4*)&As[row][c8] = *(const uint4*)(xb + (size_t)blist[row] * NI + kb + c8);
            *(uint4*)&Bs[row][c8] = *(const uint4*)(wTc + (size_t)row * NI + kb + c8);
        }
        __syncthreads();

        const int n0 = wv * 16;
#pragma unroll
        for (int k0 = 0; k0 < 4; ++k0) {
            short8 bfrag = *(const short8*)&Bs[n0 + lrc][k0 * 32 + koff];
#pragma unroll
            for (int ms = 0; ms < 4; ++ms) {
                short8 afrag = *(const short8*)&As[ms * 16 + lrc][k0 * 32 + koff];
                acc[ms] = __builtin_amdgcn_mfma_f32_16x16x32_bf16(afrag, bfrag, acc[ms], 0, 0, 0);
            }
        }
        __syncthreads();
    }

    // D layout: col = lane&15, row = (lane>>4)*4 + reg
    const int o = o0 + wv * 16 + lrc;
    const float bv = bias[o * NC + c];
    const int rbase = (lane >> 4) * 4;
#pragma unroll
    for (int ms = 0; ms < 4; ++ms) {
#pragma unroll
        for (int r = 0; r < 4; ++r) {
            int row = ms * 16 + rbase + r;
            if (m0 + row < cnt) {
                out[(size_t)blist[row] * NO + o] = acc[ms][r] + bv;
            }
        }
    }
}

extern "C" void kernel_launch(void* const* d_in, const int* in_sizes, int n_in,
                              void* d_out, int out_size, void* d_ws, size_t ws_size,
                              hipStream_t stream) {
    const float* x    = (const float*)d_in[0];   // fp32 [NB][NI]
    const int*   idx  = (const int*)d_in[1];     // int32 [NB]
    const float* w    = (const float*)d_in[2];   // fp32 [NO][NI][NC]
    const float* bias = (const float*)d_in[3];   // fp32 [NO][NC]
    float* out = (float*)d_out;                  // fp32 [NB][NO]

    char* ws = (char*)d_ws;
    unsigned int*   counts = (unsigned int*)(ws + WS_COUNTS_OFF);
    unsigned short* lists  = (unsigned short*)(ws + WS_LISTS_OFF);
    unsigned short* xb     = (unsigned short*)(ws + WS_XB_OFF);
    unsigned short* wT     = (unsigned short*)(ws + WS_WT_OFF);

    hipMemsetAsync(counts, 0, NC * sizeof(unsigned int), stream);
    k_bucket<<<NB / 256, 256, 0, stream>>>(idx, counts, lists);
    k_convert_x<<<(NB * NI / 8) / 256, 256, 0, stream>>>(x, xb);
    k_transpose<<<(NO * NI) / 256, 256, 0, stream>>>(w, wT);
    dim3 grid(NC, NO / 64, NB / 64);
    k_gemm<<<grid, 256, 0, stream>>>(xb, wT, bias, counts, lists, out);
}

// Round 3
// 82.966 us; speedup vs baseline: 1.1879x; 1.1879x over previous
//
#include <hip/hip_runtime.h>
#include <hip/hip_bf16.h>

// SwitchLinear: out[b,o] = sum_i x[b,i]*W[o,i,c_b] + bias[o,c_b]
// x,W,bias,out = fp32; idx = int32. B=8192 I=O=256 C=32.
// Strategy: bucket rows by channel, bf16-ize x and W (transposed), then one
// grouped MFMA GEMM. 2 dispatches total (launch-overhead-bound problem).
#define NB 8192
#define NI 256
#define NO 256
#define NC 32

typedef __attribute__((ext_vector_type(8))) short short8;   // 8 x bf16
typedef __attribute__((ext_vector_type(4))) float floatx4;  // MFMA acc

// ---- workspace layout (bytes) ----
#define WS_COUNTS_OFF 0            // uint counts[NC]
#define WS_LISTS_OFF  (4u << 10)   // ushort lists[NC][NB]
#define WS_XB_OFF     (1u << 20)   // ushort xb[NB][NI]
#define WS_WT_OFF     (5u << 20)   // ushort wT[NC][NO][NI]

static __device__ __forceinline__ unsigned short f2bf(float f) {
    __hip_bfloat16 h = __float2bfloat16(f);   // RNE
    return *(unsigned short*)&h;
}

// One fused prep kernel, block-role split:
//   blocks [0,32)        : bucket channel c = blockIdx.x (LDS counter, no memset needed)
//   blocks [32,1056)     : convert x fp32 -> xb bf16 (2048 elems/block)
//   blocks [1056,1312)   : transpose W[o][i][c] fp32 -> wT[c][o][i] bf16
#define PREP_CONV0 32
#define PREP_TRAN0 (32 + 1024)
#define PREP_BLOCKS (PREP_TRAN0 + 256)

__global__ __launch_bounds__(256) void k_prep(
        const int* __restrict__ idx,
        const float* __restrict__ x,
        const float* __restrict__ w,
        unsigned int* __restrict__ counts,
        unsigned short* __restrict__ lists,
        unsigned short* __restrict__ xb,
        unsigned short* __restrict__ wT) {
    const int bid = blockIdx.x;
    const int tid = threadIdx.x;

    if (bid < PREP_CONV0) {
        // ---- bucket: block bid owns channel c ----
        __shared__ unsigned int lcnt;
        if (tid == 0) lcnt = 0u;
        __syncthreads();
        const int c = bid;
        const int4* idx4 = (const int4*)idx;
        for (int t = tid; t < NB / 4; t += 256) {
            int4 v = idx4[t];
            int b0 = t * 4;
            if (v.x == c) lists[c * NB + atomicAdd(&lcnt, 1u)] = (unsigned short)(b0 + 0);
            if (v.y == c) lists[c * NB + atomicAdd(&lcnt, 1u)] = (unsigned short)(b0 + 1);
            if (v.z == c) lists[c * NB + atomicAdd(&lcnt, 1u)] = (unsigned short)(b0 + 2);
            if (v.w == c) lists[c * NB + atomicAdd(&lcnt, 1u)] = (unsigned short)(b0 + 3);
        }
        __syncthreads();
        if (tid == 0) counts[c] = lcnt;
    } else if (bid < PREP_TRAN0) {
        // ---- convert x -> bf16, 8 elems/thread ----
        size_t t = (size_t)(bid - PREP_CONV0) * 256 + tid;   // 0..262143
        const float4* src = (const float4*)(x + t * 8);
        float4 a = src[0], b = src[1];
        unsigned short r[8];
        r[0] = f2bf(a.x); r[1] = f2bf(a.y); r[2] = f2bf(a.z); r[3] = f2bf(a.w);
        r[4] = f2bf(b.x); r[5] = f2bf(b.y); r[6] = f2bf(b.z); r[7] = f2bf(b.w);
        *(uint4*)(xb + t * 8) = *(uint4*)r;
    } else {
        // ---- transpose W: g = o*NI+i reads 32 fp32 (c-contig), scatters per c ----
        int g = (bid - PREP_TRAN0) * 256 + tid;   // 0..65535
        const float4* src = (const float4*)(w + (size_t)g * NC);
        unsigned short vals[NC];
#pragma unroll
        for (int s = 0; s < 8; ++s) {
            float4 v = src[s];
            vals[s * 4 + 0] = f2bf(v.x);
            vals[s * 4 + 1] = f2bf(v.y);
            vals[s * 4 + 2] = f2bf(v.z);
            vals[s * 4 + 3] = f2bf(v.w);
        }
#pragma unroll
        for (int c = 0; c < NC; ++c) {
            // fixed c: 64 consecutive g per wave -> 128 B contiguous store
            wT[(size_t)c * (NO * NI) + g] = vals[c];
        }
    }
}

// Grouped GEMM: grid (c, o-tile, z=8), block = 256 = 4 waves, persistent in m.
// Tile M=64 (gathered rows), N=64 outputs, K streamed 2 x 128 (bf16 LDS).
// LDS rows padded to 136 bf16 (272 B, 16B-aligned; 68 dw == 4 mod 32 -> 2-way free).
__launch_bounds__(256)
__global__ void k_gemm(const unsigned short* __restrict__ xb,
                       const unsigned short* __restrict__ wT,
                       const float* __restrict__ bias,
                       const unsigned int* __restrict__ counts,
                       const unsigned short* __restrict__ lists,
                       float* __restrict__ out) {
    const int c  = blockIdx.x;
    const int o0 = blockIdx.y * 64;
    const int cnt = (int)counts[c];

    __shared__ unsigned short As[64][136];
    __shared__ unsigned short Bs[64][136];
    __shared__ int blist[64];

    const int tid  = threadIdx.x;
    const int wv   = tid >> 6;
    const int lane = tid & 63;
    const int lrc  = lane & 15;        // A row m / B,D col n
    const int koff = (lane >> 4) * 8;  // k offset within 32-chunk
    const int rbase = (lane >> 4) * 4;

    const unsigned short* wTc = wT + ((size_t)c * NO + o0) * NI;
    const int o = o0 + wv * 16 + lrc;
    const float bv = bias[o * NC + c];

    for (int mt = blockIdx.z; mt * 64 < cnt; mt += 8) {
        const int m0 = mt * 64;
        if (tid < 64) {
            int mr = m0 + tid;
            blist[tid] = (int)lists[c * NB + (mr < cnt ? mr : m0)];
        }
        __syncthreads();

        floatx4 acc[4];
#pragma unroll
        for (int ms = 0; ms < 4; ++ms) acc[ms] = (floatx4){0.f, 0.f, 0.f, 0.f};

#pragma unroll
        for (int kt = 0; kt < 2; ++kt) {
            const int kb = kt * 128;
#pragma unroll
            for (int s = 0; s < 4; ++s) {
                int lin = tid + s * 256;   // 64 rows x 8 segs of 16B
                int row = lin >> 4;
                int c8  = (lin & 15) * 8;
                *(uint4*)&As[row][c8] = *(const uint4*)(xb + (size_t)blist[row] * NI + kb + c8);
                *(uint4*)&Bs[row][c8] = *(const uint4*)(wTc + (size_t)row * NI + kb + c8);
            }
            __syncthreads();

            const int n0 = wv * 16;
#pragma unroll
            for (int k0 = 0; k0 < 4; ++k0) {
                short8 bfrag = *(const short8*)&Bs[n0 + lrc][k0 * 32 + koff];
#pragma unroll
                for (int ms = 0; ms < 4; ++ms) {
                    short8 afrag = *(const short8*)&As[ms * 16 + lrc][k0 * 32 + koff];
                    acc[ms] = __builtin_amdgcn_mfma_f32_16x16x32_bf16(afrag, bfrag, acc[ms], 0, 0, 0);
                }
            }
            __syncthreads();
        }

        // D layout: col = lane&15, row = (lane>>4)*4 + reg
#pragma unroll
        for (int ms = 0; ms < 4; ++ms) {
#pragma unroll
            for (int r = 0; r < 4; ++r) {
                int row = ms * 16 + rbase + r;
                if (m0 + row < cnt) {
                    out[(size_t)blist[row] * NO + o] = acc[ms][r] + bv;
                }
            }
        }
        __syncthreads();   // protect blist/As/Bs before next persistent iteration
    }
}

extern "C" void kernel_launch(void* const* d_in, const int* in_sizes, int n_in,
                              void* d_out, int out_size, void* d_ws, size_t ws_size,
                              hipStream_t stream) {
    const float* x    = (const float*)d_in[0];   // fp32 [NB][NI]
    const int*   idx  = (const int*)d_in[1];     // int32 [NB]
    const float* w    = (const float*)d_in[2];   // fp32 [NO][NI][NC]
    const float* bias = (const float*)d_in[3];   // fp32 [NO][NC]
    float* out = (float*)d_out;                  // fp32 [NB][NO]

    char* ws = (char*)d_ws;
    unsigned int*   counts = (unsigned int*)(ws + WS_COUNTS_OFF);
    unsigned short* lists  = (unsigned short*)(ws + WS_LISTS_OFF);
    unsigned short* xb     = (unsigned short*)(ws + WS_XB_OFF);
    unsigned short* wT     = (unsigned short*)(ws + WS_WT_OFF);

    k_prep<<<PREP_BLOCKS, 256, 0, stream>>>(idx, x, w, counts, lists, xb, wT);
    dim3 grid(NC, NO / 64, 8);
    k_gemm<<<grid, 256, 0, stream>>>(xb, wT, bias, counts, lists, out);
}